// Round 12
// baseline (804.118 us; speedup 1.0000x reference)
//
#include <hip/hip_runtime.h>
#include <hip/hip_fp16.h>
#include <cstdint>
#include <cstddef>

typedef _Float16 f16;
typedef _Float16 half8 __attribute__((ext_vector_type(8)));
typedef _Float16 half4 __attribute__((ext_vector_type(4)));
typedef float floatx4 __attribute__((ext_vector_type(4)));

static constexpr size_t NB  = 16384;
static constexpr size_t DH  = 2048;
static constexpr size_t F1  = 1024;
static constexpr size_t F2  = 512;
static constexpr size_t CD  = 256;
static constexpr size_t KCB = 512;

// ---- d_out element offsets (all float32) ----
static constexpr size_t ZE_OFF  = 0;
static constexpr size_t ZQ_OFF  = NB * CD;
static constexpr size_t HR_OFF  = 2 * NB * CD;
static constexpr size_t IDX_OFF = 2 * NB * CD + NB * DH;

// ---- workspace byte offsets ----
static constexpr size_t O_HH   = 0;                   // h hi [NB,DH] f16
static constexpr size_t O_HL   = O_HH + NB * DH * 2;  // h lo
static constexpr size_t R1_END = O_HL + NB * DH * 2;

static constexpr size_t R_X1H = 0;                    // [NB,F1] f16
static constexpr size_t R_X1L = NB * F1 * 2;
static constexpr size_t R_X2H = 2 * NB * F1 * 2;      // [NB,F2] f16
static constexpr size_t R_X2L = R_X2H + NB * F2 * 2;
static constexpr size_t R_Y1H = 0;                    // [NB,F2] f16
static constexpr size_t R_Y2H = NB * F2 * 2;          // [NB,F1] f16

static constexpr size_t O_W1H = R1_END;
static constexpr size_t O_W1L = O_W1H + F1 * DH * 2;
static constexpr size_t O_W2H = O_W1L + F1 * DH * 2;
static constexpr size_t O_W2L = O_W2H + F2 * F1 * 2;
static constexpr size_t O_W3H = O_W2L + F2 * F1 * 2;
static constexpr size_t O_W3L = O_W3H + CD * F2 * 2;
static constexpr size_t O_CBH = O_W3L + CD * F2 * 2;
static constexpr size_t O_CBL = O_CBH + KCB * CD * 2;
static constexpr size_t O_DW1 = O_CBL + KCB * CD * 2;
static constexpr size_t O_DW2 = O_DW1 + F2 * CD * 2;
static constexpr size_t O_DW3 = O_DW2 + F1 * F2 * 2;
static constexpr size_t O_SUM = O_DW3 + DH * F1 * 2;  // 4 layers x 1024 doubles
static constexpr size_t O_SQ  = O_SUM + 4 * 1024 * 8;
static constexpr size_t O_CN  = O_SQ + 4 * 1024 * 8;  // cnorm [KCB] f32 (2KB)
static constexpr size_t O_CTR = O_CN + 2048;          // 8 ints: grid-barrier ctrs
static constexpr size_t R2    = (O_CN + 4096 + 255) & ~(size_t)255;
static constexpr size_t R2_ZEH = R2;                  // [NB,CD] f16
static constexpr size_t R2_ZEL = R2 + NB * CD * 2;
static constexpr size_t R2_S   = R2 + 2 * NB * CD * 2;   // [NB,KCB] f32
static constexpr size_t R2_ZQH = R2_S + NB * KCB * 4;    // [NB,CD] f16

#define GLLDS(src, dst)                                                          \
    __builtin_amdgcn_global_load_lds(                                            \
        (const __attribute__((address_space(1))) void*)(src),                    \
        (__attribute__((address_space(3))) void*)(dst), 16, 0, 0)

#define VMCNT(n)  asm volatile("s_waitcnt vmcnt(" #n ")" ::: "memory")

// counted lgkm wait + sched fence (rule 18); n must be compile-time constant
#define WAITC(n) do { switch (n) {                                               \
    case 0: asm volatile("s_waitcnt lgkmcnt(0)" ::: "memory"); break;            \
    case 1: asm volatile("s_waitcnt lgkmcnt(1)" ::: "memory"); break;            \
    case 2: asm volatile("s_waitcnt lgkmcnt(2)" ::: "memory"); break;            \
    case 3: asm volatile("s_waitcnt lgkmcnt(3)" ::: "memory"); break;            \
    case 4: asm volatile("s_waitcnt lgkmcnt(4)" ::: "memory"); break;            \
    case 5: asm volatile("s_waitcnt lgkmcnt(5)" ::: "memory"); break;            \
    case 6: asm volatile("s_waitcnt lgkmcnt(6)" ::: "memory"); break;            \
    default: asm volatile("s_waitcnt lgkmcnt(7)" ::: "memory"); break; }         \
    __builtin_amdgcn_sched_barrier(0); } while (0)

// device-scope grid barrier: all blocks co-resident by construction
// (exactly 256 blocks, 1 block/CU via LDS). ctr zeroed by prep_all each call.
__device__ __forceinline__ void grid_barrier(int* ctr, int nblk, int tid)
{
    __syncthreads();                       // drains vmcnt -> stats atomics done
    if (tid == 0) {
        atomicAdd(ctr, 1);
        while (atomicAdd(ctr, 0) < nblk) __builtin_amdgcn_s_sleep(2);
    }
    __syncthreads();
}

// ============================================================================
// Fused 3-product GEMM: C = Ah*Bh^T + Ah*Bl^T + Al*Bh^T, f32 accum.
// BM=MW*32, BN=256, BK=32. 8 waves (2M x 4N). LDS: 2 dbuf x 2 planes (H,L);
// plane [256 rows][64 f16]: slots 0-3 = A rows (wrapped to BM), 4-7 = B;
// XOR swizzle slot ^= (row&7). 2 barriers/K-tile; counted vmcnt(4).
// BNFUSE: epilogue computes batch stats (f64 atomics), grid-barriers, then
// applies BN affine + LReLU in-register and writes f16 hi/lo planes directly.
// ============================================================================
template<int MW, bool BIAS, bool WSPLIT, bool BNFUSE>
__global__ __launch_bounds__(512)
void gemm3_t(const f16* __restrict__ Ah_, const f16* __restrict__ Al_,
             const f16* __restrict__ Bh_, const f16* __restrict__ Bl_,
             float* __restrict__ C, const float* __restrict__ bias,
             double* __restrict__ ssum, double* __restrict__ ssq,
             const float* __restrict__ g, const float* __restrict__ b,
             int* __restrict__ ctr,
             f16* __restrict__ zeh, f16* __restrict__ zel,
             int M, int N, int K)
{
    constexpr int BM = MW * 32;
    __shared__ f16 lds[2][2][16384];
    const int tid  = threadIdx.x;
    const int lane = tid & 63;
    const int w    = tid >> 6;
    const int wr   = w >> 2, wn = w & 3;
    const int row0 = blockIdx.x * BM;
    const int col0 = blockIdx.y * 256;

    const int rr8 = lane >> 3;
    const int p   = (lane & 7) ^ rr8;
    const int rr  = w * 32 + rr8;
    const int arr = rr & (BM - 1);
    const f16* srcH = (p < 4) ? (Ah_ + (size_t)(row0 + arr) * K + p * 8)
                              : (Bh_ + (size_t)(col0 + rr) * K + (p - 4) * 8);
    const f16* srcL = (p < 4) ? (Al_ + (size_t)(row0 + arr) * K + p * 8)
                              : (Bl_ + (size_t)(col0 + rr) * K + (p - 4) * 8);
    const int dstBase = w * 32 * 64;
    const int KT = K >> 5;

    floatx4 acc[MW][4];
#pragma unroll
    for (int m = 0; m < MW; ++m)
#pragma unroll
        for (int n = 0; n < 4; ++n)
#pragma unroll
            for (int j = 0; j < 4; ++j) acc[m][n][j] = 0.f;

    const int l15 = lane & 15;
    const int sA  = lane >> 4;

    int rdA[MW], rdB[4];
#pragma unroll
    for (int m = 0; m < MW; ++m) {
        const int rA = wr * (MW * 16) + m * 16 + l15;
        rdA[m] = rA * 64 + ((sA ^ (rA & 7)) << 3);
    }
#pragma unroll
    for (int n = 0; n < 4; ++n) {
        const int rB = wn * 64 + n * 16 + l15;
        rdB[n] = rB * 64 + (((4 + sA) ^ (rB & 7)) << 3);
    }

    // prologue
#pragma unroll
    for (int j = 0; j < 4; ++j)
        GLLDS(srcH + (size_t)j * 8 * K, &lds[0][0][dstBase + j * 512]);
#pragma unroll
    for (int j = 0; j < 4; ++j)
        GLLDS(srcL + (size_t)j * 8 * K, &lds[0][1][dstBase + j * 512]);
    VMCNT(4);
    __builtin_amdgcn_s_barrier();

    half8 afh[MW], afl[MW], bfh[4], bfl[4];

    for (int kt = 0; kt < KT; ++kt) {
        const int cur = kt & 1, nxt = cur ^ 1;
        const int koff = (kt + 1 < KT ? kt + 1 : kt) << 5;
        const f16* plH = lds[cur][0];
        const f16* plL = lds[cur][1];

        // ===== phase 1 : hh =====
#pragma unroll
        for (int n = 0; n < 4; ++n) bfh[n] = *(const half8*)(plH + rdB[n]);
        afh[0] = *(const half8*)(plH + rdA[0]);
        afh[1] = *(const half8*)(plH + rdA[1]);
#pragma unroll
        for (int j = 0; j < 4; ++j)
            GLLDS(srcH + (size_t)j * 8 * K + koff, &lds[nxt][0][dstBase + j * 512]);
        WAITC(1);
        __builtin_amdgcn_s_setprio(1);
#pragma unroll
        for (int m = 0; m < MW; ++m) {
            if (m + 2 < MW) afh[m + 2] = *(const half8*)(plH + rdA[m + 2]);
#pragma unroll
            for (int n = 0; n < 4; ++n)
                acc[m][n] = __builtin_amdgcn_mfma_f32_16x16x32_f16(afh[m], bfh[n], acc[m][n], 0, 0, 0);
            if (m + 1 < MW) { if (m + 2 < MW) WAITC(1); else WAITC(0); }
        }
        __builtin_amdgcn_s_setprio(0);
        VMCNT(4);
        __builtin_amdgcn_s_barrier();

        // ===== phase 2 : hl + lh =====
#pragma unroll
        for (int n = 0; n < 4; ++n) bfl[n] = *(const half8*)(plL + rdB[n]);
        afl[0] = *(const half8*)(plL + rdA[0]);
        afl[1] = *(const half8*)(plL + rdA[1]);
#pragma unroll
        for (int j = 0; j < 4; ++j)
            GLLDS(srcL + (size_t)j * 8 * K + koff, &lds[nxt][1][dstBase + j * 512]);
        WAITC(2);
        __builtin_amdgcn_s_setprio(1);
#pragma unroll
        for (int m = 0; m < MW; ++m) {
            if (m + 2 < MW) afl[m + 2] = *(const half8*)(plL + rdA[m + 2]);
#pragma unroll
            for (int n = 0; n < 4; ++n)
                acc[m][n] = __builtin_amdgcn_mfma_f32_16x16x32_f16(afh[m], bfl[n], acc[m][n], 0, 0, 0);
        }
#pragma unroll
        for (int m = 0; m < MW; ++m) {
            WAITC(MW - 1 - m);
#pragma unroll
            for (int n = 0; n < 4; ++n)
                acc[m][n] = __builtin_amdgcn_mfma_f32_16x16x32_f16(afl[m], bfh[n], acc[m][n], 0, 0, 0);
        }
        __builtin_amdgcn_s_setprio(0);
        VMCNT(4);
        __builtin_amdgcn_s_barrier();
    }
    VMCNT(0);

    const int cb0 = col0 + wn * 64;
    const int rb0 = row0 + wr * (MW * 16) + (lane >> 4) * 4;

    if constexpr (BNFUSE) {
        // ---- stats ----
#pragma unroll
        for (int n = 0; n < 4; ++n) {
            const int col = cb0 + n * 16 + l15;
            double sd = 0.0, sq = 0.0;
#pragma unroll
            for (int m = 0; m < MW; ++m)
#pragma unroll
                for (int j = 0; j < 4; ++j) {
                    const double v = (double)acc[m][n][j];
                    sd += v; sq += v * v;
                }
            sd += __shfl_xor(sd, 16); sd += __shfl_xor(sd, 32);
            sq += __shfl_xor(sq, 16); sq += __shfl_xor(sq, 32);
            if (lane < 16) { atomicAdd(ssum + col, sd); atomicAdd(ssq + col, sq); }
        }
        grid_barrier(ctr, gridDim.x * gridDim.y, tid);
        // ---- finalize + apply + write f16 hi/lo ----
#pragma unroll
        for (int n = 0; n < 4; ++n) {
            const int col = cb0 + n * 16 + l15;
            const double mean = atomicAdd(ssum + col, 0.0) * (1.0 / (double)NB);
            const double var  = atomicAdd(ssq + col, 0.0) * (1.0 / (double)NB) - mean * mean;
            const double sc   = (double)g[col] / sqrt(var + 1e-5);
            const float scale = (float)sc;
            const float shift = (float)((double)b[col] - mean * sc);
#pragma unroll
            for (int m = 0; m < MW; ++m) {
                const int row = rb0 + m * 16;
#pragma unroll
                for (int j = 0; j < 4; ++j) {
                    float v = fmaf(acc[m][n][j], scale, shift);
                    v = v >= 0.f ? v : 0.01f * v;
                    const f16 hv = (f16)v;
                    const size_t o = (size_t)(row + j) * N + col;
                    zeh[o] = hv;
                    zel[o] = (f16)(v - (float)hv);
                }
            }
        }
    } else {
#pragma unroll
        for (int n = 0; n < 4; ++n) {
            const int col = cb0 + n * 16 + l15;
            const float bv = BIAS ? bias[col] : 0.f;
#pragma unroll
            for (int m = 0; m < MW; ++m) {
                const int row = rb0 + m * 16;
#pragma unroll
                for (int j = 0; j < 4; ++j) {
                    const float v = acc[m][n][j] + bv;
                    const size_t o = (size_t)(row + j) * N + col;
                    C[o] = v;
                    if (WSPLIT) {
                        const f16 hv = (f16)v;
                        zeh[o] = hv;
                        zel[o] = (f16)(v - (float)hv);
                    }
                }
            }
        }
    }
}

// ============================================================================
// Single-product GEMM (decoder): 1 phase/K-tile, ring-3 (stage 2 ahead),
// 1 barrier + counted vmcnt(4) per K-tile. BNFUSE as above (hi plane only).
// ============================================================================
template<int MW, bool BIAS, bool BNFUSE>
__global__ __launch_bounds__(512)
void gemm1_t(const f16* __restrict__ A_, const f16* __restrict__ B_,
             float* __restrict__ C, const float* __restrict__ bias,
             double* __restrict__ ssum, double* __restrict__ ssq,
             const float* __restrict__ g, const float* __restrict__ b,
             int* __restrict__ ctr, f16* __restrict__ yh,
             int M, int N, int K)
{
    constexpr int BM = MW * 32;
    __shared__ f16 lds[3][16384];
    const int tid  = threadIdx.x;
    const int lane = tid & 63;
    const int w    = tid >> 6;
    const int wr   = w >> 2, wn = w & 3;
    const int row0 = blockIdx.x * BM;
    const int col0 = blockIdx.y * 256;

    const int rr8 = lane >> 3;
    const int p   = (lane & 7) ^ rr8;
    const int rr  = w * 32 + rr8;
    const int arr = rr & (BM - 1);
    const f16* srcH = (p < 4) ? (A_ + (size_t)(row0 + arr) * K + p * 8)
                              : (B_ + (size_t)(col0 + rr) * K + (p - 4) * 8);
    const int dstBase = w * 32 * 64;
    const int KT = K >> 5;

    floatx4 acc[MW][4];
#pragma unroll
    for (int m = 0; m < MW; ++m)
#pragma unroll
        for (int n = 0; n < 4; ++n)
#pragma unroll
            for (int j = 0; j < 4; ++j) acc[m][n][j] = 0.f;

    const int l15 = lane & 15;
    const int sA  = lane >> 4;

    int rdA[MW], rdB[4];
#pragma unroll
    for (int m = 0; m < MW; ++m) {
        const int rA = wr * (MW * 16) + m * 16 + l15;
        rdA[m] = rA * 64 + ((sA ^ (rA & 7)) << 3);
    }
#pragma unroll
    for (int n = 0; n < 4; ++n) {
        const int rB = wn * 64 + n * 16 + l15;
        rdB[n] = rB * 64 + (((4 + sA) ^ (rB & 7)) << 3);
    }

    // prologue
#pragma unroll
    for (int j = 0; j < 4; ++j)
        GLLDS(srcH + (size_t)j * 8 * K, &lds[0][dstBase + j * 512]);
    {
        const int k1 = (KT > 1 ? 1 : 0) << 5;
#pragma unroll
        for (int j = 0; j < 4; ++j)
            GLLDS(srcH + (size_t)j * 8 * K + k1, &lds[1][dstBase + j * 512]);
    }
    VMCNT(4);
    __builtin_amdgcn_s_barrier();

    half8 afh[MW], bfh[4];

    for (int kt = 0; kt < KT; ++kt) {
        const int cur = kt % 3, tgt = (kt + 2) % 3;
        const int koff = (kt + 2 < KT ? kt + 2 : KT - 1) << 5;
        const f16* plH = lds[cur];

#pragma unroll
        for (int n = 0; n < 4; ++n) bfh[n] = *(const half8*)(plH + rdB[n]);
        afh[0] = *(const half8*)(plH + rdA[0]);
        afh[1] = *(const half8*)(plH + rdA[1]);
#pragma unroll
        for (int j = 0; j < 4; ++j)
            GLLDS(srcH + (size_t)j * 8 * K + koff, &lds[tgt][dstBase + j * 512]);
        WAITC(1);
        __builtin_amdgcn_s_setprio(1);
#pragma unroll
        for (int m = 0; m < MW; ++m) {
            if (m + 2 < MW) afh[m + 2] = *(const half8*)(plH + rdA[m + 2]);
#pragma unroll
            for (int n = 0; n < 4; ++n)
                acc[m][n] = __builtin_amdgcn_mfma_f32_16x16x32_f16(afh[m], bfh[n], acc[m][n], 0, 0, 0);
            if (m + 1 < MW) { if (m + 2 < MW) WAITC(1); else WAITC(0); }
        }
        __builtin_amdgcn_s_setprio(0);
        VMCNT(4);
        __builtin_amdgcn_s_barrier();
    }
    VMCNT(0);

    const int cb0 = col0 + wn * 64;
    const int rb0 = row0 + wr * (MW * 16) + (lane >> 4) * 4;

    if constexpr (BNFUSE) {
#pragma unroll
        for (int n = 0; n < 4; ++n) {
            const int col = cb0 + n * 16 + l15;
            double sd = 0.0, sq = 0.0;
#pragma unroll
            for (int m = 0; m < MW; ++m)
#pragma unroll
                for (int j = 0; j < 4; ++j) {
                    const double v = (double)acc[m][n][j];
                    sd += v; sq += v * v;
                }
            sd += __shfl_xor(sd, 16); sd += __shfl_xor(sd, 32);
            sq += __shfl_xor(sq, 16); sq += __shfl_xor(sq, 32);
            if (lane < 16) { atomicAdd(ssum + col, sd); atomicAdd(ssq + col, sq); }
        }
        grid_barrier(ctr, gridDim.x * gridDim.y, tid);
#pragma unroll
        for (int n = 0; n < 4; ++n) {
            const int col = cb0 + n * 16 + l15;
            const double mean = atomicAdd(ssum + col, 0.0) * (1.0 / (double)NB);
            const double var  = atomicAdd(ssq + col, 0.0) * (1.0 / (double)NB) - mean * mean;
            const double sc   = (double)g[col] / sqrt(var + 1e-5);
            const float scale = (float)sc;
            const float shift = (float)((double)b[col] - mean * sc);
#pragma unroll
            for (int m = 0; m < MW; ++m) {
                const int row = rb0 + m * 16;
#pragma unroll
                for (int j = 0; j < 4; ++j) {
                    float v = fmaf(acc[m][n][j], scale, shift);
                    v = v >= 0.f ? v : 0.01f * v;
                    yh[(size_t)(row + j) * N + col] = (f16)v;
                }
            }
        }
    } else {
#pragma unroll
        for (int n = 0; n < 4; ++n) {
            const int col = cb0 + n * 16 + l15;
            const float bv = BIAS ? bias[col] : 0.f;
#pragma unroll
            for (int m = 0; m < MW; ++m) {
                const int row = rb0 + m * 16;
#pragma unroll
                for (int j = 0; j < 4; ++j)
                    C[(size_t)(row + j) * N + col] = acc[m][n][j] + bv;
            }
        }
    }
}

// generic 32x32 transpose body: W[K,N] f32 -> T[N,K] f16 (+optional lo)
__device__ __forceinline__ void tr_body(const float* __restrict__ W, f16* __restrict__ Thi,
                                        f16* __restrict__ Tlo, int K, int N,
                                        int bx, int by, bool split)
{
    __shared__ float tile[32][33];
    const int x = threadIdx.x;
    const int y = threadIdx.y;
    const int nt = bx * 32;
    const int kt = by * 32;
#pragma unroll
    for (int i = 0; i < 32; i += 8)
        tile[y + i][x] = W[(size_t)(kt + y + i) * N + nt + x];
    __syncthreads();
#pragma unroll
    for (int i = 0; i < 32; i += 8) {
        const float v = tile[x][y + i];
        const size_t o = (size_t)(nt + y + i) * K + kt + x;
        const f16 hv = (f16)v;
        Thi[o] = hv;
        if (split) Tlo[o] = (f16)(v - (float)hv);
    }
}

// ONE launch: split h, weight transposes, cnorm, zero BN accumulators + ctrs
__global__ void prep_all(const float* __restrict__ h,
                         const float* __restrict__ ew1, const float* __restrict__ ew2,
                         const float* __restrict__ ew3, const float* __restrict__ cbk,
                         const float* __restrict__ dw1, const float* __restrict__ dw2,
                         const float* __restrict__ dw3,
                         f16* __restrict__ Hh, f16* __restrict__ Hl,
                         f16* __restrict__ W1h, f16* __restrict__ W1l,
                         f16* __restrict__ W2h, f16* __restrict__ W2l,
                         f16* __restrict__ W3h, f16* __restrict__ W3l,
                         f16* __restrict__ CBh, f16* __restrict__ CBl,
                         f16* __restrict__ D1t, f16* __restrict__ D2t,
                         f16* __restrict__ D3t, float* __restrict__ cn,
                         double* __restrict__ sums, int* __restrict__ ctrs)
{
    const int bidx = blockIdx.x;
    const int tid = threadIdx.y * 32 + threadIdx.x;
    if (bidx < 2048) {
        const size_t n4 = NB * DH / 4;
        const size_t stride = (size_t)2048 * 256;
        for (size_t i = (size_t)bidx * 256 + tid; i < n4; i += stride) {
            const floatx4 x = ((const floatx4*)h)[i];
            half4 hh, ll;
#pragma unroll
            for (int j = 0; j < 4; ++j) {
                const float v = x[j];
                const f16 hv = (f16)v;
                hh[j] = hv;
                ll[j] = (f16)(v - (float)hv);
            }
            ((half4*)Hh)[i] = hh;
            ((half4*)Hl)[i] = ll;
        }
        return;
    }
    const int b = bidx - 2048;
    if (b < 2048)      tr_body(ew1, W1h, W1l, DH, F1, b % 32, b / 32, true);
    else if (b < 2560) { const int c = b - 2048; tr_body(ew2, W2h, W2l, F1, F2, c % 16, c / 16, true); }
    else if (b < 2688) { const int c = b - 2560; tr_body(ew3, W3h, W3l, F2, CD, c % 8,  c / 8,  true); }
    else if (b < 2816) { const int c = b - 2688; tr_body(cbk, CBh, CBl, CD, KCB, c % 16, c / 16, true); }
    else if (b < 2944) { const int c = b - 2816; tr_body(dw1, D1t, nullptr, CD, F2, c % 16, c / 16, false); }
    else if (b < 3456) { const int c = b - 2944; tr_body(dw2, D2t, nullptr, F2, F1, c % 32, c / 32, false); }
    else if (b < 5504) { const int c = b - 3456; tr_body(dw3, D3t, nullptr, F1, DH, c % 64, c / 64, false); }
    else if (b < 5506) {
        const int k = (b - 5504) * 256 + tid;
        if (k < (int)KCB) {
            double s = 0.0;
            for (int d = 0; d < (int)CD; ++d) {
                const float v = cbk[(size_t)d * KCB + k];
                s += (double)v * v;
            }
            cn[k] = (float)s;
        }
    } else {
        const int idx = (b - 5506) * 256 + tid;
        for (int i = idx; i < 8192; i += 2048) sums[i] = 0.0;
        if (idx < 8) ctrs[idx] = 0;
    }
}

// dist[b,k] = cnorm[k] - 2*S[b,k]; first-index argmin; gather z_q
__global__ void argmin_gather(const float* __restrict__ S, const float* __restrict__ cn,
                              const float* __restrict__ cb, float* __restrict__ zq,
                              float* __restrict__ idx_out, f16* __restrict__ zqh)
{
    const int lane = threadIdx.x & 63;
    const int row  = blockIdx.x * 4 + (threadIdx.x >> 6);
    const float* Sr = S + (size_t)row * KCB;
    float best = 3.4e38f;
    int bi = 0;
#pragma unroll
    for (int i = 0; i < 8; ++i) {
        const int k = lane + 64 * i;
        const float d = cn[k] - 2.f * Sr[k];
        if (d < best) { best = d; bi = k; }
    }
#pragma unroll
    for (int off = 32; off > 0; off >>= 1) {
        const float ob = __shfl_xor(best, off);
        const int   oi = __shfl_xor(bi, off);
        if (ob < best || (ob == best && oi < bi)) { best = ob; bi = oi; }
    }
    if (lane == 0) idx_out[row] = (float)bi;
#pragma unroll
    for (int i = 0; i < 4; ++i) {
        const int d = lane + 64 * i;
        const float v = cb[(size_t)d * KCB + bi];
        zq[(size_t)row * CD + d]  = v;
        zqh[(size_t)row * CD + d] = (f16)v;
    }
}

extern "C" void kernel_launch(void* const* d_in, const int* in_sizes, int n_in,
                              void* d_out, int out_size, void* d_ws, size_t ws_size,
                              hipStream_t stream)
{
    (void)in_sizes; (void)n_in; (void)out_size; (void)ws_size;
    const float* h   = (const float*)d_in[0];
    const float* ew1 = (const float*)d_in[1];
    const float* bg1 = (const float*)d_in[2];
    const float* bb1 = (const float*)d_in[3];
    const float* ew2 = (const float*)d_in[4];
    const float* bg2 = (const float*)d_in[5];
    const float* bb2 = (const float*)d_in[6];
    const float* ew3 = (const float*)d_in[7];
    const float* eb3 = (const float*)d_in[8];
    const float* cb  = (const float*)d_in[9];
    const float* dw1 = (const float*)d_in[10];
    const float* dg1 = (const float*)d_in[11];
    const float* db1 = (const float*)d_in[12];
    const float* dw2 = (const float*)d_in[13];
    const float* dg2 = (const float*)d_in[14];
    const float* db2 = (const float*)d_in[15];
    const float* dw3 = (const float*)d_in[16];
    const float* db3 = (const float*)d_in[17];

    char* ws = (char*)d_ws;
    float* out = (float*)d_out;

    f16* Hh  = (f16*)(ws + O_HH);
    f16* Hl  = (f16*)(ws + O_HL);
    f16* W1h = (f16*)(ws + O_W1H);
    f16* W1l = (f16*)(ws + O_W1L);
    f16* W2h = (f16*)(ws + O_W2H);
    f16* W2l = (f16*)(ws + O_W2L);
    f16* W3h = (f16*)(ws + O_W3H);
    f16* W3l = (f16*)(ws + O_W3L);
    f16* CBh = (f16*)(ws + O_CBH);
    f16* CBl = (f16*)(ws + O_CBL);
    f16* D1t = (f16*)(ws + O_DW1);
    f16* D2t = (f16*)(ws + O_DW2);
    f16* D3t = (f16*)(ws + O_DW3);
    double* sum0 = (double*)(ws + O_SUM);
    double* sq0  = (double*)(ws + O_SQ);
    float* cn  = (float*)(ws + O_CN);
    int* ctrs  = (int*)(ws + O_CTR);

    f16*  X1h = (f16*)(ws + R_X1H);
    f16*  X1l = (f16*)(ws + R_X1L);
    f16*  X2h = (f16*)(ws + R_X2H);
    f16*  X2l = (f16*)(ws + R_X2L);
    f16*  Zeh = (f16*)(ws + R2_ZEH);
    f16*  Zel = (f16*)(ws + R2_ZEL);
    float* Sb  = (float*)(ws + R2_S);
    f16*  Zqh = (f16*)(ws + R2_ZQH);
    f16*  Y1h = (f16*)(ws + R_Y1H);
    f16*  Y2h = (f16*)(ws + R_Y2H);

    // one prep launch: split h + weight transposes + cnorm + zero sums/ctrs
    prep_all<<<7564, dim3(32, 8), 0, stream>>>(h, ew1, ew2, ew3, cb, dw1, dw2, dw3,
        Hh, Hl, W1h, W1l, W2h, W2l, W3h, W3l, CBh, CBl, D1t, D2t, D3t, cn, sum0, ctrs);

    // ---- encoder (BN+LReLU fused into GEMM epilogues via grid barrier) ----
    gemm3_t<8, false, false, true><<<dim3(NB / 256, F1 / 256), 512, 0, stream>>>(
        Hh, Hl, W1h, W1l, nullptr, nullptr, sum0, sq0, bg1, bb1, ctrs + 0,
        X1h, X1l, NB, F1, DH);

    gemm3_t<4, false, false, true><<<dim3(NB / 128, F2 / 256), 512, 0, stream>>>(
        X1h, X1l, W2h, W2l, nullptr, nullptr, sum0 + 1024, sq0 + 1024, bg2, bb2, ctrs + 1,
        X2h, X2l, NB, F2, F1);

    gemm3_t<4, true, true, false><<<dim3(NB / 128, CD / 256), 512, 0, stream>>>(
        X2h, X2l, W3h, W3l, out + ZE_OFF, eb3, nullptr, nullptr, nullptr, nullptr, nullptr,
        Zeh, Zel, NB, CD, F2);

    // ---- quantize ----
    gemm3_t<4, false, false, false><<<dim3(NB / 128, KCB / 256), 512, 0, stream>>>(
        Zeh, Zel, CBh, CBl, Sb, nullptr, nullptr, nullptr, nullptr, nullptr, nullptr,
        nullptr, nullptr, NB, KCB, CD);
    argmin_gather<<<NB / 4, 256, 0, stream>>>(Sb, cn, cb, out + ZQ_OFF, out + IDX_OFF, Zqh);

    // ---- decoder ----
    gemm1_t<4, false, true><<<dim3(NB / 128, F2 / 256), 512, 0, stream>>>(
        Zqh, D1t, nullptr, nullptr, sum0 + 2048, sq0 + 2048, dg1, db1, ctrs + 2,
        Y1h, NB, F2, CD);

    gemm1_t<8, false, true><<<dim3(NB / 256, F1 / 256), 512, 0, stream>>>(
        Y1h, D2t, nullptr, nullptr, sum0 + 3072, sq0 + 3072, dg2, db2, ctrs + 3,
        Y2h, NB, F1, F2);

    gemm1_t<8, true, false><<<dim3(NB / 256, DH / 256), 512, 0, stream>>>(
        Y2h, D3t, out + HR_OFF, db3, nullptr, nullptr, nullptr, nullptr, nullptr,
        nullptr, NB, DH, F1);
}

// Round 13
// 577.442 us; speedup vs baseline: 1.3926x; 1.3926x over previous
//
#include <hip/hip_runtime.h>
#include <hip/hip_fp16.h>
#include <cstdint>
#include <cstddef>

typedef _Float16 f16;
typedef _Float16 half8 __attribute__((ext_vector_type(8)));
typedef _Float16 half4 __attribute__((ext_vector_type(4)));
typedef float floatx4 __attribute__((ext_vector_type(4)));

static constexpr size_t NB  = 16384;
static constexpr size_t DH  = 2048;
static constexpr size_t F1  = 1024;
static constexpr size_t F2  = 512;
static constexpr size_t CD  = 256;
static constexpr size_t KCB = 512;

// ---- d_out element offsets (all float32) ----
static constexpr size_t ZE_OFF  = 0;
static constexpr size_t ZQ_OFF  = NB * CD;
static constexpr size_t HR_OFF  = 2 * NB * CD;
static constexpr size_t IDX_OFF = 2 * NB * CD + NB * DH;

// ---- workspace byte offsets ----
static constexpr size_t O_HH   = 0;                   // h hi [NB,DH] f16
static constexpr size_t O_HL   = O_HH + NB * DH * 2;  // h lo
static constexpr size_t R1_END = O_HL + NB * DH * 2;

static constexpr size_t R_X1H = 0;                    // [NB,F1] f16
static constexpr size_t R_X1L = NB * F1 * 2;
static constexpr size_t R_X2F = 2 * NB * F1 * 2;      // [NB,F2] f32
static constexpr size_t R_X2H = R_X2F + NB * F2 * 4;
static constexpr size_t R_X2L = R_X2H + NB * F2 * 2;
static constexpr size_t R_Y1F = 0;                    // [NB,F2] f32
static constexpr size_t R_Y1H = NB * F2 * 4;          // [NB,F2] f16
static constexpr size_t R_Y2H = 0;                    // [NB,F1] f16

static constexpr size_t O_W1H = R1_END;
static constexpr size_t O_W1L = O_W1H + F1 * DH * 2;
static constexpr size_t O_W2H = O_W1L + F1 * DH * 2;
static constexpr size_t O_W2L = O_W2H + F2 * F1 * 2;
static constexpr size_t O_W3H = O_W2L + F2 * F1 * 2;
static constexpr size_t O_W3L = O_W3H + CD * F2 * 2;
static constexpr size_t O_CBH = O_W3L + CD * F2 * 2;
static constexpr size_t O_CBL = O_CBH + KCB * CD * 2;
static constexpr size_t O_DW1 = O_CBL + KCB * CD * 2;
static constexpr size_t O_DW2 = O_DW1 + F2 * CD * 2;
static constexpr size_t O_DW3 = O_DW2 + F1 * F2 * 2;
static constexpr size_t O_SUM = O_DW3 + DH * F1 * 2;  // 4 layers x 1024 doubles
static constexpr size_t O_SQ  = O_SUM + 4 * 1024 * 8;
static constexpr size_t O_SC  = O_SQ + 4 * 1024 * 8;
static constexpr size_t O_SH  = O_SC + 4 * 1024 * 4;
static constexpr size_t O_CN  = O_SH + 4 * 1024 * 4;
static constexpr size_t R2    = (O_CN + 4096 + 255) & ~(size_t)255;
static constexpr size_t R2_X1F = R2;                  // [NB,F1] f32
static constexpr size_t R2_ZEH = R2;                  // [NB,CD] f16
static constexpr size_t R2_ZEL = R2 + NB * CD * 2;
static constexpr size_t R2_S   = R2 + 2 * NB * CD * 2;   // [NB,KCB] f32
static constexpr size_t R2_ZQH = R2_S + NB * KCB * 4;    // [NB,CD] f16
static constexpr size_t R2_Y2F = R2;                  // [NB,F1] f32

#define GLLDS(src, dst)                                                          \
    __builtin_amdgcn_global_load_lds(                                            \
        (const __attribute__((address_space(1))) void*)(src),                    \
        (__attribute__((address_space(3))) void*)(dst), 16, 0, 0)

#define VMCNT(n)  asm volatile("s_waitcnt vmcnt(" #n ")" ::: "memory")

// counted lgkm wait + sched fence (rule 18); n must be compile-time constant
#define WAITC(n) do { switch (n) {                                               \
    case 0: asm volatile("s_waitcnt lgkmcnt(0)" ::: "memory"); break;            \
    case 1: asm volatile("s_waitcnt lgkmcnt(1)" ::: "memory"); break;            \
    case 2: asm volatile("s_waitcnt lgkmcnt(2)" ::: "memory"); break;            \
    case 3: asm volatile("s_waitcnt lgkmcnt(3)" ::: "memory"); break;            \
    case 4: asm volatile("s_waitcnt lgkmcnt(4)" ::: "memory"); break;            \
    case 5: asm volatile("s_waitcnt lgkmcnt(5)" ::: "memory"); break;            \
    case 6: asm volatile("s_waitcnt lgkmcnt(6)" ::: "memory"); break;            \
    default: asm volatile("s_waitcnt lgkmcnt(7)" ::: "memory"); break; }         \
    __builtin_amdgcn_sched_barrier(0); } while (0)

// ============================================================================
// Fused 3-product GEMM: C = Ah*Bh^T + Ah*Bl^T + Al*Bh^T, f32 accum.
// BM=MW*32, BN=256, BK=32. 8 waves (2M x 4N). LDS: 2 dbuf x 2 planes (H,L);
// plane [256 rows][64 f16]: slots 0-3 = A rows (wrapped to BM), 4-7 = B;
// XOR swizzle slot ^= (row&7) on pre-swizzled global source and ds_read.
// 2 barriers/K-tile; counted vmcnt(4) (never 0). Fragment reads pipelined
// against MFMA clusters with counted lgkmcnt.  [serial-floor verified]
// ============================================================================
template<int MW, bool BIAS, bool STATS, bool WSPLIT>
__global__ __launch_bounds__(512)
void gemm3_t(const f16* __restrict__ Ah_, const f16* __restrict__ Al_,
             const f16* __restrict__ Bh_, const f16* __restrict__ Bl_,
             float* __restrict__ C, const float* __restrict__ bias,
             double* __restrict__ ssum, double* __restrict__ ssq,
             f16* __restrict__ zeh, f16* __restrict__ zel,
             int M, int N, int K)
{
    constexpr int BM = MW * 32;
    __shared__ f16 lds[2][2][16384];   // [buf][plane H/L][256*64]
    const int tid  = threadIdx.x;
    const int lane = tid & 63;
    const int w    = tid >> 6;
    const int wr   = w >> 2, wn = w & 3;
    const int row0 = blockIdx.x * BM;
    const int col0 = blockIdx.y * 256;

    const int rr8 = lane >> 3;               // row within 8-row chunk
    const int p   = (lane & 7) ^ rr8;        // logical slot this lane fetches
    const int rr  = w * 32 + rr8;            // plane row (j adds 8)
    const int arr = rr & (BM - 1);           // A row (wrap-dup when BM < 256)
    const f16* srcH = (p < 4) ? (Ah_ + (size_t)(row0 + arr) * K + p * 8)
                              : (Bh_ + (size_t)(col0 + rr) * K + (p - 4) * 8);
    const f16* srcL = (p < 4) ? (Al_ + (size_t)(row0 + arr) * K + p * 8)
                              : (Bl_ + (size_t)(col0 + rr) * K + (p - 4) * 8);
    const int dstBase = w * 32 * 64;
    const int KT = K >> 5;

    floatx4 acc[MW][4];
#pragma unroll
    for (int m = 0; m < MW; ++m)
#pragma unroll
        for (int n = 0; n < 4; ++n)
#pragma unroll
            for (int j = 0; j < 4; ++j) acc[m][n][j] = 0.f;

    const int l15 = lane & 15;
    const int sA  = lane >> 4;

    int rdA[MW], rdB[4];
#pragma unroll
    for (int m = 0; m < MW; ++m) {
        const int rA = wr * (MW * 16) + m * 16 + l15;
        rdA[m] = rA * 64 + ((sA ^ (rA & 7)) << 3);
    }
#pragma unroll
    for (int n = 0; n < 4; ++n) {
        const int rB = wn * 64 + n * 16 + l15;
        rdB[n] = rB * 64 + (((4 + sA) ^ (rB & 7)) << 3);
    }

    // prologue: stage H(0), L(0) into buf 0
#pragma unroll
    for (int j = 0; j < 4; ++j)
        GLLDS(srcH + (size_t)j * 8 * K, &lds[0][0][dstBase + j * 512]);
#pragma unroll
    for (int j = 0; j < 4; ++j)
        GLLDS(srcL + (size_t)j * 8 * K, &lds[0][1][dstBase + j * 512]);
    VMCNT(4);                                 // H(0) landed (L(0) in flight)
    __builtin_amdgcn_s_barrier();

    half8 afh[MW], afl[MW], bfh[4], bfl[4];

    for (int kt = 0; kt < KT; ++kt) {
        const int cur = kt & 1, nxt = cur ^ 1;
        const int koff = (kt + 1 < KT ? kt + 1 : kt) << 5;
        const f16* plH = lds[cur][0];
        const f16* plL = lds[cur][1];

        // ===== phase 1 : hh =====
#pragma unroll
        for (int n = 0; n < 4; ++n) bfh[n] = *(const half8*)(plH + rdB[n]);
        afh[0] = *(const half8*)(plH + rdA[0]);
        afh[1] = *(const half8*)(plH + rdA[1]);
#pragma unroll
        for (int j = 0; j < 4; ++j)
            GLLDS(srcH + (size_t)j * 8 * K + koff, &lds[nxt][0][dstBase + j * 512]);
        WAITC(1);                             // bfh + afh0 ready; afh1 in flight
        __builtin_amdgcn_s_setprio(1);
#pragma unroll
        for (int m = 0; m < MW; ++m) {
            if (m + 2 < MW) afh[m + 2] = *(const half8*)(plH + rdA[m + 2]);
#pragma unroll
            for (int n = 0; n < 4; ++n)
                acc[m][n] = __builtin_amdgcn_mfma_f32_16x16x32_f16(afh[m], bfh[n], acc[m][n], 0, 0, 0);
            if (m + 1 < MW) { if (m + 2 < MW) WAITC(1); else WAITC(0); }
        }
        __builtin_amdgcn_s_setprio(0);
        VMCNT(4);                             // L(kt) landed (H(kt+1) in flight)
        __builtin_amdgcn_s_barrier();

        // ===== phase 2 : hl + lh =====
#pragma unroll
        for (int n = 0; n < 4; ++n) bfl[n] = *(const half8*)(plL + rdB[n]);
        afl[0] = *(const half8*)(plL + rdA[0]);
        afl[1] = *(const half8*)(plL + rdA[1]);
#pragma unroll
        for (int j = 0; j < 4; ++j)
            GLLDS(srcL + (size_t)j * 8 * K + koff, &lds[nxt][1][dstBase + j * 512]);
        WAITC(2);                             // bfl ready; afl0,1 in flight
        __builtin_amdgcn_s_setprio(1);
#pragma unroll
        for (int m = 0; m < MW; ++m) {        // hl product (needs bfl only)
            if (m + 2 < MW) afl[m + 2] = *(const half8*)(plL + rdA[m + 2]);
#pragma unroll
            for (int n = 0; n < 4; ++n)
                acc[m][n] = __builtin_amdgcn_mfma_f32_16x16x32_f16(afh[m], bfl[n], acc[m][n], 0, 0, 0);
        }
#pragma unroll
        for (int m = 0; m < MW; ++m) {        // lh product, gated per-m
            WAITC(MW - 1 - m);
#pragma unroll
            for (int n = 0; n < 4; ++n)
                acc[m][n] = __builtin_amdgcn_mfma_f32_16x16x32_f16(afl[m], bfh[n], acc[m][n], 0, 0, 0);
        }
        __builtin_amdgcn_s_setprio(0);
        VMCNT(4);                             // H(kt+1) landed (L(kt+1) in flight)
        __builtin_amdgcn_s_barrier();
    }
    VMCNT(0);

    // epilogue: C/D layout col = lane&15, row = (lane>>4)*4 + j
    const int cb0 = col0 + wn * 64;
    const int rb0 = row0 + wr * (MW * 16) + (lane >> 4) * 4;
#pragma unroll
    for (int n = 0; n < 4; ++n) {
        const int col = cb0 + n * 16 + l15;
        const float bv = BIAS ? bias[col] : 0.f;
        double sd = 0.0, sq = 0.0;
#pragma unroll
        for (int m = 0; m < MW; ++m) {
            const int row = rb0 + m * 16;
#pragma unroll
            for (int j = 0; j < 4; ++j) {
                const float v = acc[m][n][j] + bv;
                const size_t o = (size_t)(row + j) * N + col;
                C[o] = v;
                if (WSPLIT) {
                    const f16 hv = (f16)v;
                    zeh[o] = hv;
                    zel[o] = (f16)(v - (float)hv);
                }
                if (STATS) { sd += (double)v; sq += (double)v * (double)v; }
            }
        }
        if (STATS) {
            sd += __shfl_xor(sd, 16);
            sd += __shfl_xor(sd, 32);
            sq += __shfl_xor(sq, 16);
            sq += __shfl_xor(sq, 32);
            if (lane < 16) {
                atomicAdd(ssum + col, sd);
                atomicAdd(ssq + col, sq);
            }
        }
    }
}

// ============================================================================
// Single-product GEMM (decoder): 1 phase/K-tile, ring-3 (stage 2 ahead),
// 1 barrier + counted vmcnt(4) per K-tile. Pipelined fragment reads.
// ============================================================================
template<int MW, bool BIAS, bool STATS>
__global__ __launch_bounds__(512)
void gemm1_t(const f16* __restrict__ A_, const f16* __restrict__ B_,
             float* __restrict__ C, const float* __restrict__ bias,
             double* __restrict__ ssum, double* __restrict__ ssq,
             int M, int N, int K)
{
    constexpr int BM = MW * 32;
    __shared__ f16 lds[3][16384];
    const int tid  = threadIdx.x;
    const int lane = tid & 63;
    const int w    = tid >> 6;
    const int wr   = w >> 2, wn = w & 3;
    const int row0 = blockIdx.x * BM;
    const int col0 = blockIdx.y * 256;

    const int rr8 = lane >> 3;
    const int p   = (lane & 7) ^ rr8;
    const int rr  = w * 32 + rr8;
    const int arr = rr & (BM - 1);
    const f16* srcH = (p < 4) ? (A_ + (size_t)(row0 + arr) * K + p * 8)
                              : (B_ + (size_t)(col0 + rr) * K + (p - 4) * 8);
    const int dstBase = w * 32 * 64;
    const int KT = K >> 5;

    floatx4 acc[MW][4];
#pragma unroll
    for (int m = 0; m < MW; ++m)
#pragma unroll
        for (int n = 0; n < 4; ++n)
#pragma unroll
            for (int j = 0; j < 4; ++j) acc[m][n][j] = 0.f;

    const int l15 = lane & 15;
    const int sA  = lane >> 4;

    int rdA[MW], rdB[4];
#pragma unroll
    for (int m = 0; m < MW; ++m) {
        const int rA = wr * (MW * 16) + m * 16 + l15;
        rdA[m] = rA * 64 + ((sA ^ (rA & 7)) << 3);
    }
#pragma unroll
    for (int n = 0; n < 4; ++n) {
        const int rB = wn * 64 + n * 16 + l15;
        rdB[n] = rB * 64 + (((4 + sA) ^ (rB & 7)) << 3);
    }

    // prologue: stage (0)->buf0, (1)->buf1
#pragma unroll
    for (int j = 0; j < 4; ++j)
        GLLDS(srcH + (size_t)j * 8 * K, &lds[0][dstBase + j * 512]);
    {
        const int k1 = (KT > 1 ? 1 : 0) << 5;
#pragma unroll
        for (int j = 0; j < 4; ++j)
            GLLDS(srcH + (size_t)j * 8 * K + k1, &lds[1][dstBase + j * 512]);
    }
    VMCNT(4);
    __builtin_amdgcn_s_barrier();

    half8 afh[MW], bfh[4];

    for (int kt = 0; kt < KT; ++kt) {
        const int cur = kt % 3, tgt = (kt + 2) % 3;
        const int koff = (kt + 2 < KT ? kt + 2 : KT - 1) << 5;
        const f16* plH = lds[cur];

#pragma unroll
        for (int n = 0; n < 4; ++n) bfh[n] = *(const half8*)(plH + rdB[n]);
        afh[0] = *(const half8*)(plH + rdA[0]);
        afh[1] = *(const half8*)(plH + rdA[1]);
#pragma unroll
        for (int j = 0; j < 4; ++j)
            GLLDS(srcH + (size_t)j * 8 * K + koff, &lds[tgt][dstBase + j * 512]);
        WAITC(1);
        __builtin_amdgcn_s_setprio(1);
#pragma unroll
        for (int m = 0; m < MW; ++m) {
            if (m + 2 < MW) afh[m + 2] = *(const half8*)(plH + rdA[m + 2]);
#pragma unroll
            for (int n = 0; n < 4; ++n)
                acc[m][n] = __builtin_amdgcn_mfma_f32_16x16x32_f16(afh[m], bfh[n], acc[m][n], 0, 0, 0);
            if (m + 1 < MW) { if (m + 2 < MW) WAITC(1); else WAITC(0); }
        }
        __builtin_amdgcn_s_setprio(0);
        VMCNT(4);                             // buf(kt+1) landed, buf(kt+2) in flight
        __builtin_amdgcn_s_barrier();
    }
    VMCNT(0);

    const int cb0 = col0 + wn * 64;
    const int rb0 = row0 + wr * (MW * 16) + (lane >> 4) * 4;
#pragma unroll
    for (int n = 0; n < 4; ++n) {
        const int col = cb0 + n * 16 + l15;
        const float bv = BIAS ? bias[col] : 0.f;
        double sd = 0.0, sq = 0.0;
#pragma unroll
        for (int m = 0; m < MW; ++m) {
            const int row = rb0 + m * 16;
#pragma unroll
            for (int j = 0; j < 4; ++j) {
                const float v = acc[m][n][j] + bv;
                C[(size_t)(row + j) * N + col] = v;
                if (STATS) { sd += (double)v; sq += (double)v * (double)v; }
            }
        }
        if (STATS) {
            sd += __shfl_xor(sd, 16);
            sd += __shfl_xor(sd, 32);
            sq += __shfl_xor(sq, 16);
            sq += __shfl_xor(sq, 32);
            if (lane < 16) {
                atomicAdd(ssum + col, sd);
                atomicAdd(ssq + col, sq);
            }
        }
    }
}

__global__ void bn_finalize(const double* __restrict__ ssum, const double* __restrict__ ssq,
                            const float* __restrict__ g, const float* __restrict__ b,
                            float* __restrict__ scale, float* __restrict__ shift, int N)
{
    const int j = blockIdx.x * blockDim.x + threadIdx.x;
    if (j < N) {
        const double inv = 1.0 / (double)NB;
        const double mean = ssum[j] * inv;
        const double var  = ssq[j] * inv - mean * mean;
        const double sc   = (double)g[j] / sqrt(var + 1e-5);
        scale[j] = (float)sc;
        shift[j] = (float)((double)b[j] - mean * sc);
    }
}

// BN affine + LeakyReLU, output f16 (optionally hi/lo split)
template<bool SPLIT>
__global__ void bn_apply(const float* __restrict__ X, const float* __restrict__ scale,
                         const float* __restrict__ shift, f16* __restrict__ Yhi,
                         f16* __restrict__ Ylo, size_t n4, int Nmask)
{
    const size_t stride = (size_t)gridDim.x * blockDim.x;
    for (size_t i = (size_t)blockIdx.x * blockDim.x + threadIdx.x; i < n4; i += stride) {
        const floatx4 x = ((const floatx4*)X)[i];
        const int col = (int)((i * 4) & (size_t)Nmask);
        half4 h, l;
#pragma unroll
        for (int j = 0; j < 4; ++j) {
            float v = x[j] * scale[col + j] + shift[col + j];
            v = v >= 0.f ? v : 0.01f * v;
            const f16 hv = (f16)v;
            h[j] = hv;
            if (SPLIT) l[j] = (f16)(v - (float)hv);
        }
        ((half4*)Yhi)[i] = h;
        if (SPLIT) ((half4*)Ylo)[i] = l;
    }
}

// generic 32x32 transpose body: W[K,N] f32 -> T[N,K] f16 (+optional lo)
__device__ __forceinline__ void tr_body(const float* __restrict__ W, f16* __restrict__ Thi,
                                        f16* __restrict__ Tlo, int K, int N,
                                        int bx, int by, bool split)
{
    __shared__ float tile[32][33];
    const int x = threadIdx.x;
    const int y = threadIdx.y;
    const int nt = bx * 32;
    const int kt = by * 32;
#pragma unroll
    for (int i = 0; i < 32; i += 8)
        tile[y + i][x] = W[(size_t)(kt + y + i) * N + nt + x];
    __syncthreads();
#pragma unroll
    for (int i = 0; i < 32; i += 8) {
        const float v = tile[x][y + i];
        const size_t o = (size_t)(nt + y + i) * K + kt + x;
        const f16 hv = (f16)v;
        Thi[o] = hv;
        if (split) Tlo[o] = (f16)(v - (float)hv);
    }
}

// ONE launch: split h, weight transposes, cnorm, zero BN accumulators
__global__ void prep_all(const float* __restrict__ h,
                         const float* __restrict__ ew1, const float* __restrict__ ew2,
                         const float* __restrict__ ew3, const float* __restrict__ cbk,
                         const float* __restrict__ dw1, const float* __restrict__ dw2,
                         const float* __restrict__ dw3,
                         f16* __restrict__ Hh, f16* __restrict__ Hl,
                         f16* __restrict__ W1h, f16* __restrict__ W1l,
                         f16* __restrict__ W2h, f16* __restrict__ W2l,
                         f16* __restrict__ W3h, f16* __restrict__ W3l,
                         f16* __restrict__ CBh, f16* __restrict__ CBl,
                         f16* __restrict__ D1t, f16* __restrict__ D2t,
                         f16* __restrict__ D3t, float* __restrict__ cn,
                         double* __restrict__ sums)
{
    const int bidx = blockIdx.x;
    const int tid = threadIdx.y * 32 + threadIdx.x;
    if (bidx < 2048) {
        const size_t n4 = NB * DH / 4;
        const size_t stride = (size_t)2048 * 256;
        for (size_t i = (size_t)bidx * 256 + tid; i < n4; i += stride) {
            const floatx4 x = ((const floatx4*)h)[i];
            half4 hh, ll;
#pragma unroll
            for (int j = 0; j < 4; ++j) {
                const float v = x[j];
                const f16 hv = (f16)v;
                hh[j] = hv;
                ll[j] = (f16)(v - (float)hv);
            }
            ((half4*)Hh)[i] = hh;
            ((half4*)Hl)[i] = ll;
        }
        return;
    }
    const int b = bidx - 2048;
    if (b < 2048)      tr_body(ew1, W1h, W1l, DH, F1, b % 32, b / 32, true);
    else if (b < 2560) { const int c = b - 2048; tr_body(ew2, W2h, W2l, F1, F2, c % 16, c / 16, true); }
    else if (b < 2688) { const int c = b - 2560; tr_body(ew3, W3h, W3l, F2, CD, c % 8,  c / 8,  true); }
    else if (b < 2816) { const int c = b - 2688; tr_body(cbk, CBh, CBl, CD, KCB, c % 16, c / 16, true); }
    else if (b < 2944) { const int c = b - 2816; tr_body(dw1, D1t, nullptr, CD, F2, c % 16, c / 16, false); }
    else if (b < 3456) { const int c = b - 2944; tr_body(dw2, D2t, nullptr, F2, F1, c % 32, c / 32, false); }
    else if (b < 5504) { const int c = b - 3456; tr_body(dw3, D3t, nullptr, F1, DH, c % 64, c / 64, false); }
    else if (b < 5506) {
        const int k = (b - 5504) * 256 + tid;
        if (k < (int)KCB) {
            double s = 0.0;
            for (int d = 0; d < (int)CD; ++d) {
                const float v = cbk[(size_t)d * KCB + k];
                s += (double)v * v;
            }
            cn[k] = (float)s;
        }
    } else {
        const int idx = (b - 5506) * 256 + tid;
        for (int i = idx; i < 8192; i += 2048) sums[i] = 0.0;
    }
}

// dist[b,k] = cnorm[k] - 2*S[b,k]; first-index argmin; gather z_q
__global__ void argmin_gather(const float* __restrict__ S, const float* __restrict__ cn,
                              const float* __restrict__ cb, float* __restrict__ zq,
                              float* __restrict__ idx_out, f16* __restrict__ zqh)
{
    const int lane = threadIdx.x & 63;
    const int row  = blockIdx.x * 4 + (threadIdx.x >> 6);
    const float* Sr = S + (size_t)row * KCB;
    float best = 3.4e38f;
    int bi = 0;
#pragma unroll
    for (int i = 0; i < 8; ++i) {
        const int k = lane + 64 * i;
        const float d = cn[k] - 2.f * Sr[k];
        if (d < best) { best = d; bi = k; }
    }
#pragma unroll
    for (int off = 32; off > 0; off >>= 1) {
        const float ob = __shfl_xor(best, off);
        const int   oi = __shfl_xor(bi, off);
        if (ob < best || (ob == best && oi < bi)) { best = ob; bi = oi; }
    }
    if (lane == 0) idx_out[row] = (float)bi;
#pragma unroll
    for (int i = 0; i < 4; ++i) {
        const int d = lane + 64 * i;
        const float v = cb[(size_t)d * KCB + bi];
        zq[(size_t)row * CD + d]  = v;
        zqh[(size_t)row * CD + d] = (f16)v;
    }
}

extern "C" void kernel_launch(void* const* d_in, const int* in_sizes, int n_in,
                              void* d_out, int out_size, void* d_ws, size_t ws_size,
                              hipStream_t stream)
{
    (void)in_sizes; (void)n_in; (void)out_size; (void)ws_size;
    const float* h   = (const float*)d_in[0];
    const float* ew1 = (const float*)d_in[1];
    const float* bg1 = (const float*)d_in[2];
    const float* bb1 = (const float*)d_in[3];
    const float* ew2 = (const float*)d_in[4];
    const float* bg2 = (const float*)d_in[5];
    const float* bb2 = (const float*)d_in[6];
    const float* ew3 = (const float*)d_in[7];
    const float* eb3 = (const float*)d_in[8];
    const float* cb  = (const float*)d_in[9];
    const float* dw1 = (const float*)d_in[10];
    const float* dg1 = (const float*)d_in[11];
    const float* db1 = (const float*)d_in[12];
    const float* dw2 = (const float*)d_in[13];
    const float* dg2 = (const float*)d_in[14];
    const float* db2 = (const float*)d_in[15];
    const float* dw3 = (const float*)d_in[16];
    const float* db3 = (const float*)d_in[17];

    char* ws = (char*)d_ws;
    float* out = (float*)d_out;

    f16* Hh  = (f16*)(ws + O_HH);
    f16* Hl  = (f16*)(ws + O_HL);
    f16* W1h = (f16*)(ws + O_W1H);
    f16* W1l = (f16*)(ws + O_W1L);
    f16* W2h = (f16*)(ws + O_W2H);
    f16* W2l = (f16*)(ws + O_W2L);
    f16* W3h = (f16*)(ws + O_W3H);
    f16* W3l = (f16*)(ws + O_W3L);
    f16* CBh = (f16*)(ws + O_CBH);
    f16* CBl = (f16*)(ws + O_CBL);
    f16* D1t = (f16*)(ws + O_DW1);
    f16* D2t = (f16*)(ws + O_DW2);
    f16* D3t = (f16*)(ws + O_DW3);
    double* sum0 = (double*)(ws + O_SUM);
    double* sq0  = (double*)(ws + O_SQ);
    float* sc0 = (float*)(ws + O_SC);
    float* sh0 = (float*)(ws + O_SH);
    float* cn  = (float*)(ws + O_CN);

    float* X1f = (float*)(ws + R2_X1F);
    f16*  X1h = (f16*)(ws + R_X1H);
    f16*  X1l = (f16*)(ws + R_X1L);
    float* X2f = (float*)(ws + R_X2F);
    f16*  X2h = (f16*)(ws + R_X2H);
    f16*  X2l = (f16*)(ws + R_X2L);
    f16*  Zeh = (f16*)(ws + R2_ZEH);
    f16*  Zel = (f16*)(ws + R2_ZEL);
    float* Sb  = (float*)(ws + R2_S);
    f16*  Zqh = (f16*)(ws + R2_ZQH);
    float* Y1f = (float*)(ws + R_Y1F);
    f16*  Y1h = (f16*)(ws + R_Y1H);
    float* Y2f = (float*)(ws + R2_Y2F);
    f16*  Y2h = (f16*)(ws + R_Y2H);

    // one prep launch: split h + weight transposes + cnorm + zero sums
    prep_all<<<7564, dim3(32, 8), 0, stream>>>(h, ew1, ew2, ew3, cb, dw1, dw2, dw3,
        Hh, Hl, W1h, W1l, W2h, W2l, W3h, W3l, CBh, CBl, D1t, D2t, D3t, cn, sum0);

    // ---- encoder ----
    gemm3_t<8, false, true, false><<<dim3(NB / 256, F1 / 256), 512, 0, stream>>>(
        Hh, Hl, W1h, W1l, X1f, nullptr, sum0, sq0, nullptr, nullptr, NB, F1, DH);
    bn_finalize<<<4, 256, 0, stream>>>(sum0, sq0, bg1, bb1, sc0, sh0, F1);
    bn_apply<true><<<2048, 256, 0, stream>>>(X1f, sc0, sh0, X1h, X1l, NB * F1 / 4, (int)F1 - 1);

    gemm3_t<4, false, true, false><<<dim3(NB / 128, F2 / 256), 512, 0, stream>>>(
        X1h, X1l, W2h, W2l, X2f, nullptr, sum0 + 1024, sq0 + 1024, nullptr, nullptr, NB, F2, F1);
    bn_finalize<<<2, 256, 0, stream>>>(sum0 + 1024, sq0 + 1024, bg2, bb2, sc0 + 1024, sh0 + 1024, F2);
    bn_apply<true><<<2048, 256, 0, stream>>>(X2f, sc0 + 1024, sh0 + 1024, X2h, X2l, NB * F2 / 4, (int)F2 - 1);

    gemm3_t<4, true, false, true><<<dim3(NB / 128, CD / 256), 512, 0, stream>>>(
        X2h, X2l, W3h, W3l, out + ZE_OFF, eb3, nullptr, nullptr, Zeh, Zel, NB, CD, F2);

    // ---- quantize ----
    gemm3_t<4, false, false, false><<<dim3(NB / 128, KCB / 256), 512, 0, stream>>>(
        Zeh, Zel, CBh, CBl, Sb, nullptr, nullptr, nullptr, nullptr, nullptr, NB, KCB, CD);
    argmin_gather<<<NB / 4, 256, 0, stream>>>(Sb, cn, cb, out + ZQ_OFF, out + IDX_OFF, Zqh);

    // ---- decoder ----
    gemm1_t<4, false, true><<<dim3(NB / 128, F2 / 256), 512, 0, stream>>>(
        Zqh, D1t, Y1f, nullptr, sum0 + 2048, sq0 + 2048, NB, F2, CD);
    bn_finalize<<<2, 256, 0, stream>>>(sum0 + 2048, sq0 + 2048, dg1, db1, sc0 + 2048, sh0 + 2048, F2);
    bn_apply<false><<<2048, 256, 0, stream>>>(Y1f, sc0 + 2048, sh0 + 2048, Y1h, nullptr, NB * F2 / 4, (int)F2 - 1);

    gemm1_t<8, false, true><<<dim3(NB / 256, F1 / 256), 512, 0, stream>>>(
        Y1h, D2t, Y2f, nullptr, sum0 + 3072, sq0 + 3072, NB, F1, F2);
    bn_finalize<<<4, 256, 0, stream>>>(sum0 + 3072, sq0 + 3072, dg2, db2, sc0 + 3072, sh0 + 3072, F1);
    bn_apply<false><<<2048, 256, 0, stream>>>(Y2f, sc0 + 3072, sh0 + 3072, Y2h, nullptr, NB * F1 / 4, (int)F1 - 1);

    gemm1_t<8, true, false><<<dim3(NB / 256, DH / 256), 512, 0, stream>>>(
        Y2h, D3t, out + HR_OFF, db3, nullptr, nullptr, NB, DH, F1);
}